// Round 7
// baseline (273.906 us; speedup 1.0000x reference)
//
#include <hip/hip_runtime.h>

// WeatherLSTM round 7: R4 skeleton + ZERO-transcendental activations.
//  - R3-R6 invariance (dur ~175 regardless of barriers/waves/LDS) back-solves
//    to v_exp/v_rcp occupying the SIMD issue port ~30 cyc each (trans unit
//    blocks all waves). Fix: synthesize exp2/rcp from pipelined 2-cyc VALU:
//      exp2s: rndne + deg-4 poly (4 FMA) + exponent-bit add  (~9 instr)
//      rcps : magic-constant guess + 2 Newton iters          (~5 instr)
//    err: exp2 4e-5 rel, rcp 1.4e-6 rel — both << f16 h-quant (5e-4).
//  - Everything else = R4 (proven): 256 blocks x 512 thr (8 waves, 2/SIMD);
//    wave owns 8 units as 2 M-tiles (adjacent-unit pairing, packed b32
//    h-writes); single barrier/iter; iter k computes L0(k)+L1(k-1) sharing
//    h0(k-1) ds_reads; x table in LDS; weights prescaled log2e (2log2e g).
//  - MFMA layouts per m89/m91/m120 (verified R2-R6: absmax 4.88e-4).

typedef _Float16 h8 __attribute__((ext_vector_type(8)));
typedef _Float16 h4 __attribute__((ext_vector_type(4)));
typedef float f4 __attribute__((ext_vector_type(4)));

#define ROWB 208
#define HBUF (16 * ROWB)          // 3328 B per h buffer
#define XTAB_OFF 0
#define XTAB_BYTES (169 * 256)    // 43264 B (row 168 = zero pad)
#define H0_OFF XTAB_BYTES
#define H1_OFF (H0_OFF + 2 * HBUF)
#define SMEM_TOTAL (H1_OFF + 2 * HBUF)   // 56576 B

#define K1F 1.4426950408889634f   // log2(e)
#define K2F 2.8853900817779268f   // 2*log2(e)

// ---- trans-free primitives ----
// 2^x for |x| <= ~120: round-to-even split + deg-4 poly + exponent-bit add.
__device__ __forceinline__ float exp2s(float x) {
  float n = __builtin_rintf(x);
  float r = x - n;
  float p = fmaf(r, fmaf(r, fmaf(r, fmaf(r, 0.0096181291f, 0.0555041087f),
                                 0.2402265069f), 0.6931471806f), 1.0f);
  int e = (int)n;
  return __builtin_bit_cast(float, __builtin_bit_cast(int, p) + (e << 23));
}
// 1/x for positive normal x: bit-hack seed + 2 Newton-Raphson steps.
__device__ __forceinline__ float rcps(float x) {
  float y = __builtin_bit_cast(float, 0x7EF311C3u - __builtin_bit_cast(unsigned, x));
  y = y * fmaf(-x, y, 2.0f);
  y = y * fmaf(-x, y, 2.0f);
  return y;
}

__device__ __forceinline__ f4 mfma16(h8 a, h8 b, f4 c) {
  return __builtin_amdgcn_mfma_f32_16x16x32_f16(a, b, c, 0, 0, 0);
}

__device__ __forceinline__ h8 load_w8s(const float* __restrict__ p, float sc) {
  h8 r;
#pragma unroll
  for (int j = 0; j < 8; j++) r[j] = (_Float16)(p[j] * sc);
  return r;
}

__device__ __forceinline__ unsigned packh2(float a, float b) {
  unsigned lo = (unsigned)__builtin_bit_cast(unsigned short, (_Float16)a);
  unsigned hi = (unsigned)__builtin_bit_cast(unsigned short, (_Float16)b);
  return lo | (hi << 16);
}

// a[0]=i,a[1]=f,a[3]=o prescaled K1F; a[2]=g prescaled K2F.
// Shared-rcp gates + fused i*tanh(g) = B*D*(Eg-1)*R, R=1/(ABCD). No trans.
__device__ __forceinline__ void lstm_act(f4 a, float& c, float& h) {
  float Ei = exp2s(-a[0]);
  float Ef = exp2s(-a[1]);
  float Eg = exp2s(a[2]);
  float Eo = exp2s(-a[3]);
  float A = 1.f + Ei, B = 1.f + Ef, C = 1.f + Eg, D = 1.f + Eo;
  float AB = A * B, CD = C * D, BD = B * D;
  float R  = rcps(AB * CD);
  float fv = (A * CD) * R;               // sigm(f)
  float ig = (BD * (Eg - 1.f)) * R;      // sigm(i)*tanh(g)
  float ov = (AB * C) * R;               // sigm(o)
  c = fmaf(fv, c, ig);
  // tanh(c): clamp arg to +-100 (guards exp-bit overflow; tanh there = 1-2^-99)
  float carg = fminf(fmaxf(c * K2F, -100.f), 100.f);
  float r2 = rcps(exp2s(carg) + 1.f);
  h = ov * fmaf(-2.f, r2, 1.f);
}

extern "C" __global__ void __launch_bounds__(512, 2)
weather_lstm_mfma7(const float* __restrict__ x,
                   const float* __restrict__ Wih0, const float* __restrict__ Whh0,
                   const float* __restrict__ bih0, const float* __restrict__ bhh0,
                   const float* __restrict__ Wih1, const float* __restrict__ Whh1,
                   const float* __restrict__ bih1, const float* __restrict__ bhh1,
                   const float* __restrict__ W1, const float* __restrict__ b1,
                   const float* __restrict__ W2, const float* __restrict__ b2,
                   float* __restrict__ out)
{
  __shared__ __align__(16) unsigned char smem[SMEM_TOTAL];
  const int tid  = threadIdx.x;
  const int lane = tid & 63;
  const int w    = tid >> 6;      // wave 0..7 -> units w*8..w*8+7
  const int col  = lane & 15;     // sample index (B-frag n / C col)
  const int quad = lane >> 4;     // 0..3
  const int sB   = blockIdx.x * 16;

  // ---- A-frag row decode: m = lane&15 = ul*4 + g; tile T unit = w*8+2*ul+T
  const int g_  = col & 3;
  const int ul_ = col >> 2;
  const float asc = (g_ == 2) ? K2F : K1F;
  int arow[2];
  arow[0] = g_ * 64 + w * 8 + 2 * ul_ + 0;
  arow[1] = g_ * 64 + w * 8 + 2 * ul_ + 1;

  // ---- load + prescale weight A-frags (once) ----
  h8 a0[2][3], a1i[2][2], a1h[2][2];
#pragma unroll
  for (int T = 0; T < 2; T++) {
    const int r = arow[T];
#pragma unroll
    for (int f = 0; f < 2; f++) {
      a0[T][f]  = load_w8s(Whh0 + r * 64 + f * 32 + quad * 8, asc);
      a1i[T][f] = load_w8s(Wih1 + r * 64 + f * 32 + quad * 8, asc);
      a1h[T][f] = load_w8s(Whh1 + r * 64 + f * 32 + quad * 8, asc);
    }
    h8 xw = {};
    if (quad == 0) {
#pragma unroll
      for (int j = 0; j < 4; j++) xw[j] = (_Float16)(Wih0[r * 4 + j] * asc);
    }
    a0[T][2] = xw;
  }

  // ---- biases (prescaled): lane C rows reg -> gate reg, unit w*8+2*quad+T
  f4 bias0v[2], bias1v[2];
#pragma unroll
  for (int T = 0; T < 2; T++) {
#pragma unroll
    for (int reg = 0; reg < 4; reg++) {
      const int rr = reg * 64 + w * 8 + 2 * quad + T;
      const float bs = (reg == 2) ? K2F : K1F;
      bias0v[T][reg] = (bih0[rr] + bhh0[rr]) * bs;
      bias1v[T][reg] = (bih1[rr] + bhh1[rr]) * bs;
    }
  }

  // ---- zero LDS, build x table ----
  for (int idx = tid; idx < SMEM_TOTAL / 4; idx += 512) ((int*)smem)[idx] = 0;
  __syncthreads();
  for (int idx = tid; idx < 16 * 168; idx += 512) {
    const int c_ = idx / 168, t_ = idx - c_ * 168;
    f4 xv = *(const f4*)(x + ((size_t)(sB + c_) * 168 + t_) * 4);
    h4 xh;
#pragma unroll
    for (int j = 0; j < 4; j++) xh[j] = (_Float16)xv[j];
    *(h4*)(smem + XTAB_OFF + t_ * 256 + c_ * 16) = xh;
  }
  __syncthreads();

  float c0[2] = {0.f, 0.f}, c1[2] = {0.f, 0.f};
  float hl[2] = {0.f, 0.f};
  const int bo = col * ROWB + quad * 16;               // B-frag byte offset
  const int wo = col * ROWB + (w * 8 + 2 * quad) * 2;  // packed h-write offset
  const unsigned char* xp = smem + XTAB_OFF + col * 16;

  for (int k = 0; k <= 168; k++) {
    const int kb = k & 1, kbn = kb ^ 1;
    const unsigned char* h0r = smem + H0_OFF + kbn * HBUF;  // h0(k-1)
    unsigned char*       h0w = smem + H0_OFF + kb  * HBUF;  // h0(k)
    const unsigned char* h1r = smem + H1_OFF + kb  * HBUF;  // h1(k-2)
    unsigned char*       h1w = smem + H1_OFF + kbn * HBUF;  // h1(k-1)

    // ---- shared ds_reads ----
    h8 b0  = *(const h8*)(h0r + bo);         // h0(k-1) k 0..31
    h8 b1v = *(const h8*)(h0r + bo + 64);    // h0(k-1) k 32..63
    h8 bx  = *(const h8*)(xp + k * 256);     // x(k) (quad0 data; others A=0)
    h8 q0  = *(const h8*)(h1r + bo);         // h1(k-2) k 0..31
    h8 q1  = *(const h8*)(h1r + bo + 64);    // h1(k-2) k 32..63

    // ---- 14 MFMAs, 4 independent chains ----
    f4 A0 = mfma16(a0[0][0], b0, bias0v[0]);     // L0 tile0
    f4 A1 = mfma16(a0[1][0], b0, bias0v[1]);     // L0 tile1
    f4 C0 = mfma16(a1i[0][0], b0, bias1v[0]);    // L1 tile0
    f4 C1 = mfma16(a1i[1][0], b0, bias1v[1]);    // L1 tile1
    A0 = mfma16(a0[0][1], b1v, A0);
    A1 = mfma16(a0[1][1], b1v, A1);
    C0 = mfma16(a1i[0][1], b1v, C0);
    C1 = mfma16(a1i[1][1], b1v, C1);
    A0 = mfma16(a0[0][2], bx, A0);
    A1 = mfma16(a0[1][2], bx, A1);
    C0 = mfma16(a1h[0][0], q0, C0);
    C1 = mfma16(a1h[1][0], q0, C1);
    C0 = mfma16(a1h[0][1], q1, C0);
    C1 = mfma16(a1h[1][1], q1, C1);

    // ---- L0 activations (discard at k==168) ----
    if (k < 168) {
      float h0o[2];
      lstm_act(A0, c0[0], h0o[0]);
      lstm_act(A1, c0[1], h0o[1]);
      *(unsigned*)(h0w + wo) = packh2(h0o[0], h0o[1]);
    }
    // ---- L1 activations (discard at k==0) ----
    if (k > 0) {
      lstm_act(C0, c1[0], hl[0]);
      lstm_act(C1, c1[1], hl[1]);
      *(unsigned*)(h1w + wo) = packh2(hl[0], hl[1]);
    }
    __syncthreads();
  }

  // ---------- MLP head (x table region dead; overlay) ----------
  float* fh = (float*)smem;              // [16][64] final h2, fp32
#pragma unroll
  for (int T = 0; T < 2; T++)
    fh[col * 64 + (w * 8 + 2 * quad + T)] = hl[T];
  __syncthreads();

  {
    const int u = tid & 63, grp = tid >> 6;  // 8 grps x 2 samples
    float za0 = b1[u], za1 = b1[u];
    const float* w1r = W1 + u * 64;
    const float* f0 = fh + (grp * 2 + 0) * 64;
    const float* f1 = fh + (grp * 2 + 1) * 64;
    for (int j = 0; j < 64; j++) {
      float wv = w1r[j];
      za0 += wv * f0[j];
      za1 += wv * f1[j];
    }
    float* zl = (float*)(smem + 4096);     // [16][64]
    zl[(grp * 2 + 0) * 64 + u] = fmaxf(za0, 0.f);
    zl[(grp * 2 + 1) * 64 + u] = fmaxf(za1, 0.f);
  }
  __syncthreads();

  if (tid < 192) {
    const float* zl = (const float*)(smem + 4096);
    const int s = tid / 12, o = tid - s * 12;
    float a = b2[o];
    for (int j = 0; j < 64; j++) a += W2[o * 64 + j] * zl[s * 64 + j];
    out[(sB + s) * 12 + o] = a;
  }
}

extern "C" void kernel_launch(void* const* d_in, const int* in_sizes, int n_in,
                              void* d_out, int out_size, void* d_ws, size_t ws_size,
                              hipStream_t stream) {
  (void)in_sizes; (void)n_in; (void)d_ws; (void)ws_size; (void)out_size;
  const float* x    = (const float*)d_in[0];
  const float* Wih0 = (const float*)d_in[1];
  const float* Whh0 = (const float*)d_in[2];
  const float* bih0 = (const float*)d_in[3];
  const float* bhh0 = (const float*)d_in[4];
  const float* Wih1 = (const float*)d_in[5];
  const float* Whh1 = (const float*)d_in[6];
  const float* bih1 = (const float*)d_in[7];
  const float* bhh1 = (const float*)d_in[8];
  const float* W1   = (const float*)d_in[9];
  const float* b1   = (const float*)d_in[10];
  const float* W2   = (const float*)d_in[11];
  const float* b2   = (const float*)d_in[12];

  weather_lstm_mfma7<<<dim3(256), dim3(512), 0, stream>>>(
      x, Wih0, Whh0, bih0, bhh0, Wih1, Whh1, bih1, bhh1, W1, b1, W2, b2,
      (float*)d_out);
}

// Round 8
// 232.857 us; speedup vs baseline: 1.1763x; 1.1763x over previous
//
#include <hip/hip_runtime.h>

// WeatherLSTM round 8: de-phased producer/consumer wave groups, NO barriers
// in the t-loop.
//  - grid 256 x 512 thr (8 waves). Waves 0-3 (group A) run layer 0 for all
//    168 steps; waves 4-7 (group B) run layer 1 lagged one step. Wave i goes
//    to SIMD i%4 -> each SIMD hosts one A + one B wave in different phases
//    (A's trans-storm overlaps B's MFMA/ds_read): attacks the ~630 cyc/iter
//    barrier-aligned idle that R3-R6 proved invariant.
//  - Sync: LDS epoch counters, workgroup-scope acquire/release atomics.
//      aCnt: A waves inc after writing h0(k)   (4 per iter)
//      bCnt: B waves inc after writing h1(k)
//    A iter k: wait aCnt>=4k (own group, h0(k-1)); every 4th iter wait
//    bCnt>=4k (ring-depth-4 throttle). B iter k: wait bCnt>=4k (own h1),
//    aCnt>=4(k+1) (h0(k) ready). A strictly ahead of B -> deadlock-free;
//    all 8 waves co-resident (one block/CU).
//  - h0: 4-slot ring; h1: 2-slot; ROWB=208 strided f16 rows (R2-proven).
//  - Wave owns 16 units as 4 M-tiles (R6 mapping, packed b32 h-writes).
//  - Acts: hardware v_exp/v_rcp (R7 proved polys are 2x worse), weights
//    prescaled log2e / 2log2e, shared-rcp + fused i*tanh(g).
//  - MFMA layouts per m89/m91/m120 (verified R2-R7: absmax 4.88e-4).

typedef _Float16 h8 __attribute__((ext_vector_type(8)));
typedef _Float16 h4 __attribute__((ext_vector_type(4)));
typedef float f4 __attribute__((ext_vector_type(4)));

#define ROWB 208
#define HBUF (16 * ROWB)            // 3328 B per h slot
#define XTAB_OFF 0
#define XTAB_BYTES (168 * 256)      // 43008 B
#define H0_OFF XTAB_BYTES           // 4 slots (ring)
#define H1_OFF (H0_OFF + 4 * HBUF)  // 2 slots
#define CNT_OFF (H1_OFF + 2 * HBUF)
#define SMEM_TOTAL (CNT_OFF + 128)  // 63104 B

#define K1F 1.4426950408889634f     // log2(e)
#define K2F 2.8853900817779268f     // 2*log2(e)

__device__ __forceinline__ float exp2_(float x) {
#if __has_builtin(__builtin_amdgcn_exp2f)
  return __builtin_amdgcn_exp2f(x);
#else
  float r; asm("v_exp_f32 %0, %1" : "=v"(r) : "v"(x)); return r;
#endif
}
__device__ __forceinline__ float rcp_(float x) {
#if __has_builtin(__builtin_amdgcn_rcpf)
  return __builtin_amdgcn_rcpf(x);
#else
  float r; asm("v_rcp_f32 %0, %1" : "=v"(r) : "v"(x)); return r;
#endif
}

__device__ __forceinline__ f4 mfma16(h8 a, h8 b, f4 c) {
  return __builtin_amdgcn_mfma_f32_16x16x32_f16(a, b, c, 0, 0, 0);
}

__device__ __forceinline__ h8 load_w8s(const float* __restrict__ p, float sc) {
  h8 r;
#pragma unroll
  for (int j = 0; j < 8; j++) r[j] = (_Float16)(p[j] * sc);
  return r;
}

__device__ __forceinline__ unsigned packh2(float a, float b) {
  unsigned lo = (unsigned)__builtin_bit_cast(unsigned short, (_Float16)a);
  unsigned hi = (unsigned)__builtin_bit_cast(unsigned short, (_Float16)b);
  return lo | (hi << 16);
}

// a[0]=i,a[1]=f,a[3]=o prescaled K1F; a[2]=g prescaled K2F.
__device__ __forceinline__ void lstm_act(f4 a, float& c, float& h) {
  float Ei = exp2_(-a[0]);
  float Ef = exp2_(-a[1]);
  float Eg = exp2_(a[2]);
  float Eo = exp2_(-a[3]);
  float A = 1.f + Ei, B = 1.f + Ef, C = 1.f + Eg, D = 1.f + Eo;
  float AB = A * B, CD = C * D, BD = B * D;
  float R  = rcp_(AB * CD);
  float fv = (A * CD) * R;               // sigm(f)
  float ig = (BD * (Eg - 1.f)) * R;      // sigm(i)*tanh(g)
  float ov = (AB * C) * R;               // sigm(o)
  c = fmaf(fv, c, ig);
  float r2 = rcp_(exp2_(c * K2F) + 1.f);
  h = ov * fmaf(-2.f, r2, 1.f);
}

__device__ __forceinline__ void spin_ge(int* p, int tgt) {
  while (__hip_atomic_load(p, __ATOMIC_ACQUIRE, __HIP_MEMORY_SCOPE_WORKGROUP) < tgt) {}
}
__device__ __forceinline__ void arrive(int* p, int lane) {
  if (lane == 0)
    __hip_atomic_fetch_add(p, 1, __ATOMIC_RELEASE, __HIP_MEMORY_SCOPE_WORKGROUP);
}

extern "C" __global__ void __launch_bounds__(512, 2)
weather_lstm_mfma8(const float* __restrict__ x,
                   const float* __restrict__ Wih0, const float* __restrict__ Whh0,
                   const float* __restrict__ bih0, const float* __restrict__ bhh0,
                   const float* __restrict__ Wih1, const float* __restrict__ Whh1,
                   const float* __restrict__ bih1, const float* __restrict__ bhh1,
                   const float* __restrict__ W1, const float* __restrict__ b1,
                   const float* __restrict__ W2, const float* __restrict__ b2,
                   float* __restrict__ out)
{
  __shared__ __align__(16) unsigned char smem[SMEM_TOTAL];
  const int tid  = threadIdx.x;
  const int lane = tid & 63;
  const int w    = tid >> 6;      // wave 0..7
  const int col  = lane & 15;     // sample index (B-frag n / C col)
  const int quad = lane >> 4;     // 0..3
  const int sB   = blockIdx.x * 16;
  const bool isA = (w < 4);
  const int gw   = w & 3;         // wave index within group
  const int ub   = gw * 16;       // unit base (16 units per wave)

  // ---- A-frag row decode: m = lane&15 = ul*4 + g ----
  const int g_  = col & 3;
  const int ul_ = col >> 2;
  const float asc = (g_ == 2) ? K2F : K1F;

  int* aCnt = (int*)(smem + CNT_OFF);
  int* bCnt = (int*)(smem + CNT_OFF + 64);

  // ---- zero LDS, build x table (all waves) ----
  for (int idx = tid; idx < SMEM_TOTAL / 4; idx += 512) ((int*)smem)[idx] = 0;
  __syncthreads();
  for (int idx = tid; idx < 16 * 168; idx += 512) {
    const int c_ = idx / 168, t_ = idx - c_ * 168;
    f4 xv = *(const f4*)(x + ((size_t)(sB + c_) * 168 + t_) * 4);
    h4 xh;
#pragma unroll
    for (int j = 0; j < 4; j++) xh[j] = (_Float16)xv[j];
    *(h4*)(smem + XTAB_OFF + t_ * 256 + c_ * 16) = xh;
  }
  __syncthreads();

  const int bo  = col * ROWB + quad * 16;              // B-frag byte offset
  const int wo0 = col * ROWB + (ub + 2 * quad) * 2;    // tiles 0/1 write
  const int wo1 = wo0 + 16;                            // tiles 2/3 (+8 units)
  float hl[4] = {0.f, 0.f, 0.f, 0.f};

  if (isA) {
    // ================= group A: layer 0 =================
    h8 a0[4][3];
    f4 bias0v[4];
#pragma unroll
    for (int T = 0; T < 4; T++) {
      const int r = g_ * 64 + ub + (T >> 1) * 8 + 2 * ul_ + (T & 1);
#pragma unroll
      for (int f = 0; f < 2; f++)
        a0[T][f] = load_w8s(Whh0 + r * 64 + f * 32 + quad * 8, asc);
      h8 xw = {};
      if (quad == 0) {
#pragma unroll
        for (int j = 0; j < 4; j++) xw[j] = (_Float16)(Wih0[r * 4 + j] * asc);
      }
      a0[T][2] = xw;
      const int rr = (0) * 64;  // placeholder to keep structure clear
      (void)rr;
#pragma unroll
      for (int reg = 0; reg < 4; reg++) {
        const int rb = reg * 64 + ub + (T >> 1) * 8 + 2 * quad + (T & 1);
        const float bs = (reg == 2) ? K2F : K1F;
        bias0v[T][reg] = (bih0[rb] + bhh0[rb]) * bs;
      }
    }
    const unsigned char* xp = smem + XTAB_OFF + col * 16;
    float c0[4] = {0.f, 0.f, 0.f, 0.f};

    for (int k = 0; k < 168; k++) {
      if ((k & 3) == 0 && k > 0) spin_ge(bCnt, 4 * k);   // ring throttle
      spin_ge(aCnt, 4 * k);                               // h0(k-1) complete
      const unsigned char* h0r = smem + H0_OFF + ((k + 3) & 3) * HBUF;
      unsigned char*       h0w = smem + H0_OFF + (k & 3) * HBUF;

      h8 b0  = *(const h8*)(h0r + bo);
      h8 b1v = *(const h8*)(h0r + bo + 64);
      h8 bx  = *(const h8*)(xp + k * 256);

      f4 A[4];
#pragma unroll
      for (int T = 0; T < 4; T++) A[T] = mfma16(a0[T][0], b0, bias0v[T]);
#pragma unroll
      for (int T = 0; T < 4; T++) A[T] = mfma16(a0[T][1], b1v, A[T]);
#pragma unroll
      for (int T = 0; T < 4; T++) A[T] = mfma16(a0[T][2], bx, A[T]);

      float h0o[4];
#pragma unroll
      for (int T = 0; T < 4; T++) lstm_act(A[T], c0[T], h0o[T]);
      *(unsigned*)(h0w + wo0) = packh2(h0o[0], h0o[1]);
      *(unsigned*)(h0w + wo1) = packh2(h0o[2], h0o[3]);
      arrive(aCnt, lane);
    }
  } else {
    // ================= group B: layer 1 (lag 1) =================
    h8 a1i[4][2], a1h[4][2];
    f4 bias1v[4];
#pragma unroll
    for (int T = 0; T < 4; T++) {
      const int r = g_ * 64 + ub + (T >> 1) * 8 + 2 * ul_ + (T & 1);
#pragma unroll
      for (int f = 0; f < 2; f++) {
        a1i[T][f] = load_w8s(Wih1 + r * 64 + f * 32 + quad * 8, asc);
        a1h[T][f] = load_w8s(Whh1 + r * 64 + f * 32 + quad * 8, asc);
      }
#pragma unroll
      for (int reg = 0; reg < 4; reg++) {
        const int rb = reg * 64 + ub + (T >> 1) * 8 + 2 * quad + (T & 1);
        const float bs = (reg == 2) ? K2F : K1F;
        bias1v[T][reg] = (bih1[rb] + bhh1[rb]) * bs;
      }
    }
    float c1[4] = {0.f, 0.f, 0.f, 0.f};

    for (int k = 0; k < 168; k++) {
      spin_ge(bCnt, 4 * k);          // own group's h1(k-1) writes complete
      spin_ge(aCnt, 4 * (k + 1));    // h0(k) ready
      const unsigned char* hp = smem + H0_OFF + (k & 3) * HBUF;        // h0(k)
      const unsigned char* hq = smem + H1_OFF + ((k + 1) & 1) * HBUF;  // h1(k-1)
      unsigned char*       h1w = smem + H1_OFF + (k & 1) * HBUF;       // h1(k)

      h8 p0 = *(const h8*)(hp + bo);
      h8 p1 = *(const h8*)(hp + bo + 64);
      h8 q0 = *(const h8*)(hq + bo);
      h8 q1 = *(const h8*)(hq + bo + 64);

      f4 C[4];
#pragma unroll
      for (int T = 0; T < 4; T++) C[T] = mfma16(a1i[T][0], p0, bias1v[T]);
#pragma unroll
      for (int T = 0; T < 4; T++) C[T] = mfma16(a1i[T][1], p1, C[T]);
#pragma unroll
      for (int T = 0; T < 4; T++) C[T] = mfma16(a1h[T][0], q0, C[T]);
#pragma unroll
      for (int T = 0; T < 4; T++) C[T] = mfma16(a1h[T][1], q1, C[T]);

#pragma unroll
      for (int T = 0; T < 4; T++) lstm_act(C[T], c1[T], hl[T]);
      *(unsigned*)(h1w + wo0) = packh2(hl[0], hl[1]);
      *(unsigned*)(h1w + wo1) = packh2(hl[2], hl[3]);
      arrive(bCnt, lane);
    }
  }
  __syncthreads();

  // ---------- MLP head (x table region dead; overlay) ----------
  float* fh = (float*)smem;              // [16][64] final h2, fp32
  if (!isA) {
#pragma unroll
    for (int T = 0; T < 4; T++)
      fh[col * 64 + (ub + (T >> 1) * 8 + 2 * quad + (T & 1))] = hl[T];
  }
  __syncthreads();

  {
    const int u = tid & 63, grp = tid >> 6;  // 8 grps x 2 samples
    float za0 = b1[u], za1 = b1[u];
    const float* w1r = W1 + u * 64;
    const float* f0 = fh + (grp * 2 + 0) * 64;
    const float* f1 = fh + (grp * 2 + 1) * 64;
    for (int j = 0; j < 64; j++) {
      float wv = w1r[j];
      za0 += wv * f0[j];
      za1 += wv * f1[j];
    }
    float* zl = (float*)(smem + 8192);     // [16][64]
    zl[(grp * 2 + 0) * 64 + u] = fmaxf(za0, 0.f);
    zl[(grp * 2 + 1) * 64 + u] = fmaxf(za1, 0.f);
  }
  __syncthreads();

  if (tid < 192) {
    const float* zl = (const float*)(smem + 8192);
    const int s = tid / 12, o = tid - s * 12;
    float a = b2[o];
    for (int j = 0; j < 64; j++) a += W2[o * 64 + j] * zl[s * 64 + j];
    out[(sB + s) * 12 + o] = a;
  }
}

extern "C" void kernel_launch(void* const* d_in, const int* in_sizes, int n_in,
                              void* d_out, int out_size, void* d_ws, size_t ws_size,
                              hipStream_t stream) {
  (void)in_sizes; (void)n_in; (void)d_ws; (void)ws_size; (void)out_size;
  const float* x    = (const float*)d_in[0];
  const float* Wih0 = (const float*)d_in[1];
  const float* Whh0 = (const float*)d_in[2];
  const float* bih0 = (const float*)d_in[3];
  const float* bhh0 = (const float*)d_in[4];
  const float* Wih1 = (const float*)d_in[5];
  const float* Whh1 = (const float*)d_in[6];
  const float* bih1 = (const float*)d_in[7];
  const float* bhh1 = (const float*)d_in[8];
  const float* W1   = (const float*)d_in[9];
  const float* b1   = (const float*)d_in[10];
  const float* W2   = (const float*)d_in[11];
  const float* b2   = (const float*)d_in[12];

  weather_lstm_mfma8<<<dim3(256), dim3(512), 0, stream>>>(
      x, Wih0, Whh0, bih0, bhh0, Wih1, Whh1, bih1, bhh1, W1, b1, W2, b2,
      (float*)d_out);
}

// Round 9
// 229.749 us; speedup vs baseline: 1.1922x; 1.0135x over previous
//
#include <hip/hip_runtime.h>

// WeatherLSTM round 9: PROPERLY de-phased producer/consumer wave groups.
// R8's throttle bug (spin_ge(bCnt,4k) -> lag-1 lockstep every 4th step) and
// per-step acquire polls kept A/B phase-locked. R9:
//  - h0 ring deepened to 8 slots; A's throttle margin corrected to
//    bCnt >= 4k-28 (B consumed h0(k-8)) -> A runs ~8 steps ahead steady-state.
//  - Batched polls: each wave caches a 'safe' step horizon from one counter
//    read; loops poll-free until exhausted. B's aCnt check is pre-satisfied
//    in steady state; A polls B ~once per 8 steps.
//  - Groups' trans storms / MFMA phases / LDS bursts drift freely on each
//    SIMD (1 A-wave + 1 B-wave) -> attacks the ~1000 cyc/iter pipe-drain
//    idle that R3-R8 proved invariant under lockstep.
//  - All else from R8: waves 0-3 = layer0 (12 MFMA + 4 acts/iter), waves
//    4-7 = layer1 lag-8 (16 MFMA + 4 acts/iter); R6 4-tile unit mapping,
//    packed b32 h-writes; x table in LDS; hardware v_exp/v_rcp acts
//    (R7 proved polys worse), weights prescaled log2e / 2log2e;
//    MFMA layouts per m89/m91/m120 (verified R2-R8: absmax 4.88e-4).
// Sync invariants (deadlock-free, A strictly ahead):
//   aCnt = 4*(A steps completed), bCnt = 4*(B steps completed).
//   A@k: aCnt>=4k (siblings' h0(k-1) written);  k>=8: bCnt>=4k-28 (slot free).
//   B@k: bCnt>=4k (siblings' h1(k-1) written);  aCnt>=4(k+1) (h0(k) ready).
//   Ring safety: A@k+8 writes slot k&7 only after B consumed step k; B reads
//   h1(k-2) protected by bCnt>=4k before any slot-k&1 write.

typedef _Float16 h8 __attribute__((ext_vector_type(8)));
typedef _Float16 h4 __attribute__((ext_vector_type(4)));
typedef float f4 __attribute__((ext_vector_type(4)));

#define ROWB 208
#define HBUF (16 * ROWB)            // 3328 B per h slot
#define XTAB_OFF 0
#define XTAB_BYTES (168 * 256)      // 43008 B
#define H0_OFF XTAB_BYTES           // 8-slot ring
#define H1_OFF (H0_OFF + 8 * HBUF)  // 2 slots
#define CNT_OFF (H1_OFF + 2 * HBUF)
#define SMEM_TOTAL (CNT_OFF + 128)  // 76416 B

#define K1F 1.4426950408889634f     // log2(e)
#define K2F 2.8853900817779268f     // 2*log2(e)

__device__ __forceinline__ float exp2_(float x) {
#if __has_builtin(__builtin_amdgcn_exp2f)
  return __builtin_amdgcn_exp2f(x);
#else
  float r; asm("v_exp_f32 %0, %1" : "=v"(r) : "v"(x)); return r;
#endif
}
__device__ __forceinline__ float rcp_(float x) {
#if __has_builtin(__builtin_amdgcn_rcpf)
  return __builtin_amdgcn_rcpf(x);
#else
  float r; asm("v_rcp_f32 %0, %1" : "=v"(r) : "v"(x)); return r;
#endif
}

__device__ __forceinline__ f4 mfma16(h8 a, h8 b, f4 c) {
  return __builtin_amdgcn_mfma_f32_16x16x32_f16(a, b, c, 0, 0, 0);
}

__device__ __forceinline__ h8 load_w8s(const float* __restrict__ p, float sc) {
  h8 r;
#pragma unroll
  for (int j = 0; j < 8; j++) r[j] = (_Float16)(p[j] * sc);
  return r;
}

__device__ __forceinline__ unsigned packh2(float a, float b) {
  unsigned lo = (unsigned)__builtin_bit_cast(unsigned short, (_Float16)a);
  unsigned hi = (unsigned)__builtin_bit_cast(unsigned short, (_Float16)b);
  return lo | (hi << 16);
}

// a[0]=i,a[1]=f,a[3]=o prescaled K1F; a[2]=g prescaled K2F.
__device__ __forceinline__ void lstm_act(f4 a, float& c, float& h) {
  float Ei = exp2_(-a[0]);
  float Ef = exp2_(-a[1]);
  float Eg = exp2_(a[2]);
  float Eo = exp2_(-a[3]);
  float A = 1.f + Ei, B = 1.f + Ef, C = 1.f + Eg, D = 1.f + Eo;
  float AB = A * B, CD = C * D, BD = B * D;
  float R  = rcp_(AB * CD);
  float fv = (A * CD) * R;               // sigm(f)
  float ig = (BD * (Eg - 1.f)) * R;      // sigm(i)*tanh(g)
  float ov = (AB * C) * R;               // sigm(o)
  c = fmaf(fv, c, ig);
  float r2 = rcp_(exp2_(c * K2F) + 1.f);
  h = ov * fmaf(-2.f, r2, 1.f);
}

__device__ __forceinline__ int ld_cnt(int* p) {
  return __hip_atomic_load(p, __ATOMIC_ACQUIRE, __HIP_MEMORY_SCOPE_WORKGROUP);
}
__device__ __forceinline__ void arrive(int* p, int lane) {
  if (lane == 0)
    __hip_atomic_fetch_add(p, 1, __ATOMIC_RELEASE, __HIP_MEMORY_SCOPE_WORKGROUP);
}

extern "C" __global__ void __launch_bounds__(512, 2)
weather_lstm_mfma9(const float* __restrict__ x,
                   const float* __restrict__ Wih0, const float* __restrict__ Whh0,
                   const float* __restrict__ bih0, const float* __restrict__ bhh0,
                   const float* __restrict__ Wih1, const float* __restrict__ Whh1,
                   const float* __restrict__ bih1, const float* __restrict__ bhh1,
                   const float* __restrict__ W1, const float* __restrict__ b1,
                   const float* __restrict__ W2, const float* __restrict__ b2,
                   float* __restrict__ out)
{
  __shared__ __align__(16) unsigned char smem[SMEM_TOTAL];
  const int tid  = threadIdx.x;
  const int lane = tid & 63;
  const int w    = tid >> 6;      // wave 0..7
  const int col  = lane & 15;     // sample index (B-frag n / C col)
  const int quad = lane >> 4;     // 0..3
  const int sB   = blockIdx.x * 16;
  const bool isA = (w < 4);
  const int gw   = w & 3;         // wave index within group
  const int ub   = gw * 16;       // unit base (16 units per wave)

  const int g_  = col & 3;
  const int ul_ = col >> 2;
  const float asc = (g_ == 2) ? K2F : K1F;

  int* aCnt = (int*)(smem + CNT_OFF);
  int* bCnt = (int*)(smem + CNT_OFF + 64);

  // ---- zero LDS, build x table (all waves) ----
  for (int idx = tid; idx < SMEM_TOTAL / 4; idx += 512) ((int*)smem)[idx] = 0;
  __syncthreads();
  for (int idx = tid; idx < 16 * 168; idx += 512) {
    const int c_ = idx / 168, t_ = idx - c_ * 168;
    f4 xv = *(const f4*)(x + ((size_t)(sB + c_) * 168 + t_) * 4);
    h4 xh;
#pragma unroll
    for (int j = 0; j < 4; j++) xh[j] = (_Float16)xv[j];
    *(h4*)(smem + XTAB_OFF + t_ * 256 + c_ * 16) = xh;
  }
  __syncthreads();

  const int bo  = col * ROWB + quad * 16;              // B-frag byte offset
  const int wo0 = col * ROWB + (ub + 2 * quad) * 2;    // tiles 0/1 write
  const int wo1 = wo0 + 16;                            // tiles 2/3 (+8 units)
  float hl[4] = {0.f, 0.f, 0.f, 0.f};

  if (isA) {
    // ================= group A: layer 0 =================
    h8 a0[4][3];
    f4 bias0v[4];
#pragma unroll
    for (int T = 0; T < 4; T++) {
      const int r = g_ * 64 + ub + (T >> 1) * 8 + 2 * ul_ + (T & 1);
#pragma unroll
      for (int f = 0; f < 2; f++)
        a0[T][f] = load_w8s(Whh0 + r * 64 + f * 32 + quad * 8, asc);
      h8 xw = {};
      if (quad == 0) {
#pragma unroll
        for (int j = 0; j < 4; j++) xw[j] = (_Float16)(Wih0[r * 4 + j] * asc);
      }
      a0[T][2] = xw;
#pragma unroll
      for (int reg = 0; reg < 4; reg++) {
        const int rb = reg * 64 + ub + (T >> 1) * 8 + 2 * quad + (T & 1);
        const float bs = (reg == 2) ? K2F : K1F;
        bias0v[T][reg] = (bih0[rb] + bhh0[rb]) * bs;
      }
    }
    const unsigned char* xp = smem + XTAB_OFF + col * 16;
    float c0[4] = {0.f, 0.f, 0.f, 0.f};
    int safeA = 0;   // steps k < safeA are cleared to run

    for (int k = 0; k < 168; k++) {
      while (k >= safeA) {                      // batched poll
        int lim = (ld_cnt(aCnt) >> 2) + 1;      // siblings wrote h0(k-1)
        if (k >= 8) {
          int lim2 = (ld_cnt(bCnt) >> 2) + 8;   // ring slot k&7 free
          lim = lim < lim2 ? lim : lim2;
        }
        safeA = lim;
      }
      const unsigned char* h0r = smem + H0_OFF + ((k + 7) & 7) * HBUF;
      unsigned char*       h0w = smem + H0_OFF + (k & 7) * HBUF;

      h8 b0  = *(const h8*)(h0r + bo);
      h8 b1v = *(const h8*)(h0r + bo + 64);
      h8 bx  = *(const h8*)(xp + k * 256);

      f4 A[4];
#pragma unroll
      for (int T = 0; T < 4; T++) A[T] = mfma16(a0[T][0], b0, bias0v[T]);
#pragma unroll
      for (int T = 0; T < 4; T++) A[T] = mfma16(a0[T][1], b1v, A[T]);
#pragma unroll
      for (int T = 0; T < 4; T++) A[T] = mfma16(a0[T][2], bx, A[T]);

      float h0o[4];
#pragma unroll
      for (int T = 0; T < 4; T++) lstm_act(A[T], c0[T], h0o[T]);
      *(unsigned*)(h0w + wo0) = packh2(h0o[0], h0o[1]);
      *(unsigned*)(h0w + wo1) = packh2(h0o[2], h0o[3]);
      arrive(aCnt, lane);
    }
  } else {
    // ================= group B: layer 1 (lag ~8) =================
    h8 a1i[4][2], a1h[4][2];
    f4 bias1v[4];
#pragma unroll
    for (int T = 0; T < 4; T++) {
      const int r = g_ * 64 + ub + (T >> 1) * 8 + 2 * ul_ + (T & 1);
#pragma unroll
      for (int f = 0; f < 2; f++) {
        a1i[T][f] = load_w8s(Wih1 + r * 64 + f * 32 + quad * 8, asc);
        a1h[T][f] = load_w8s(Whh1 + r * 64 + f * 32 + quad * 8, asc);
      }
#pragma unroll
      for (int reg = 0; reg < 4; reg++) {
        const int rb = reg * 64 + ub + (T >> 1) * 8 + 2 * quad + (T & 1);
        const float bs = (reg == 2) ? K2F : K1F;
        bias1v[T][reg] = (bih1[rb] + bhh1[rb]) * bs;
      }
    }
    float c1[4] = {0.f, 0.f, 0.f, 0.f};
    int safeB = 0;

    for (int k = 0; k < 168; k++) {
      while (k >= safeB) {                      // batched poll
        int limO = (ld_cnt(bCnt) >> 2) + 1;     // siblings wrote h1(k-1)
        int limA = (ld_cnt(aCnt) >> 2);         // h0(k) ready: aCnt>=4(k+1)
        safeB = limO < limA ? limO : limA;
      }
      const unsigned char* hp = smem + H0_OFF + (k & 7) * HBUF;        // h0(k)
      const unsigned char* hq = smem + H1_OFF + ((k + 1) & 1) * HBUF;  // h1(k-1)
      unsigned char*       h1w = smem + H1_OFF + (k & 1) * HBUF;       // h1(k)

      h8 p0 = *(const h8*)(hp + bo);
      h8 p1 = *(const h8*)(hp + bo + 64);
      h8 q0 = *(const h8*)(hq + bo);
      h8 q1 = *(const h8*)(hq + bo + 64);

      f4 C[4];
#pragma unroll
      for (int T = 0; T < 4; T++) C[T] = mfma16(a1i[T][0], p0, bias1v[T]);
#pragma unroll
      for (int T = 0; T < 4; T++) C[T] = mfma16(a1i[T][1], p1, C[T]);
#pragma unroll
      for (int T = 0; T < 4; T++) C[T] = mfma16(a1h[T][0], q0, C[T]);
#pragma unroll
      for (int T = 0; T < 4; T++) C[T] = mfma16(a1h[T][1], q1, C[T]);

#pragma unroll
      for (int T = 0; T < 4; T++) lstm_act(C[T], c1[T], hl[T]);
      *(unsigned*)(h1w + wo0) = packh2(hl[0], hl[1]);
      *(unsigned*)(h1w + wo1) = packh2(hl[2], hl[3]);
      arrive(bCnt, lane);
    }
  }
  __syncthreads();

  // ---------- MLP head (x table region dead; overlay) ----------
  float* fh = (float*)smem;              // [16][64] final h2, fp32
  if (!isA) {
#pragma unroll
    for (int T = 0; T < 4; T++)
      fh[col * 64 + (ub + (T >> 1) * 8 + 2 * quad + (T & 1))] = hl[T];
  }
  __syncthreads();

  {
    const int u = tid & 63, grp = tid >> 6;  // 8 grps x 2 samples
    float za0 = b1[u], za1 = b1[u];
    const float* w1r = W1 + u * 64;
    const float* f0 = fh + (grp * 2 + 0) * 64;
    const float* f1 = fh + (grp * 2 + 1) * 64;
    for (int j = 0; j < 64; j++) {
      float wv = w1r[j];
      za0 += wv * f0[j];
      za1 += wv * f1[j];
    }
    float* zl = (float*)(smem + 8192);     // [16][64]
    zl[(grp * 2 + 0) * 64 + u] = fmaxf(za0, 0.f);
    zl[(grp * 2 + 1) * 64 + u] = fmaxf(za1, 0.f);
  }
  __syncthreads();

  if (tid < 192) {
    const float* zl = (const float*)(smem + 8192);
    const int s = tid / 12, o = tid - s * 12;
    float a = b2[o];
    for (int j = 0; j < 64; j++) a += W2[o * 64 + j] * zl[s * 64 + j];
    out[(sB + s) * 12 + o] = a;
  }
}

extern "C" void kernel_launch(void* const* d_in, const int* in_sizes, int n_in,
                              void* d_out, int out_size, void* d_ws, size_t ws_size,
                              hipStream_t stream) {
  (void)in_sizes; (void)n_in; (void)d_ws; (void)ws_size; (void)out_size;
  const float* x    = (const float*)d_in[0];
  const float* Wih0 = (const float*)d_in[1];
  const float* Whh0 = (const float*)d_in[2];
  const float* bih0 = (const float*)d_in[3];
  const float* bhh0 = (const float*)d_in[4];
  const float* Wih1 = (const float*)d_in[5];
  const float* Whh1 = (const float*)d_in[6];
  const float* bih1 = (const float*)d_in[7];
  const float* bhh1 = (const float*)d_in[8];
  const float* W1   = (const float*)d_in[9];
  const float* b1   = (const float*)d_in[10];
  const float* W2   = (const float*)d_in[11];
  const float* b2   = (const float*)d_in[12];

  weather_lstm_mfma9<<<dim3(256), dim3(512), 0, stream>>>(
      x, Wih0, Whh0, bih0, bhh0, Wih1, Whh1, bih1, bhh1, W1, b1, W2, b2,
      (float*)d_out);
}